// Round 1
// baseline (279.383 us; speedup 1.0000x reference)
//
#include <hip/hip_runtime.h>

#define CROP_H 14
#define CROP_W 14
#define IMG_B 8
#define IMG_C 256
#define IMG_H 100
#define IMG_W 152
#define NBOX 1000
#define PLANE (IMG_H * IMG_W)                 // 15200
#define POS (CROP_H * CROP_W)                 // 196
#define OUT_PER_BOX (IMG_C * POS)             // 50176

__global__ __launch_bounds__(256) void CropAndResize_16630113370849_kernel(
    const float* __restrict__ image,
    const float* __restrict__ boxes,
    const int* __restrict__ box_ind,
    float* __restrict__ out)
{
    __shared__ int   s_ti[CROP_H], s_bi[CROP_H];
    __shared__ int   s_li[CROP_W], s_ri[CROP_W];
    __shared__ float s_yl[CROP_H], s_xl[CROP_W];
    __shared__ int   s_yv[CROP_H], s_xv[CROP_W];
    __shared__ int   s_b;

    const int n   = blockIdx.x;
    const int tid = threadIdx.x;

    if (tid == 0) s_b = box_ind[n];

    const float y1 = boxes[n * 4 + 0];
    const float x1 = boxes[n * 4 + 1];
    const float y2 = boxes[n * 4 + 2];
    const float x2 = boxes[n * 4 + 3];

    if (tid < CROP_H) {
        // h_scale = (y2 - y1) * (H-1) / (CROP_H-1), all fp32 round-to-nearest, no FMA
        const float hs   = __fdiv_rn(__fmul_rn(__fsub_rn(y2, y1), (float)(IMG_H - 1)),
                                     (float)(CROP_H - 1));
        const float in_y = __fadd_rn(__fmul_rn(y1, (float)(IMG_H - 1)),
                                     __fmul_rn((float)tid, hs));
        s_yv[tid] = (in_y >= 0.0f) && (in_y <= (float)(IMG_H - 1));
        const float top = floorf(in_y);
        s_yl[tid] = __fsub_rn(in_y, top);
        const float tc = fminf(fmaxf(top, 0.0f), (float)(IMG_H - 1));
        const float bc = fminf(fmaxf(__fadd_rn(top, 1.0f), 0.0f), (float)(IMG_H - 1));
        s_ti[tid] = (int)tc;
        s_bi[tid] = (int)bc;
    } else if (tid < CROP_H + CROP_W) {
        const int x = tid - CROP_H;
        const float ws   = __fdiv_rn(__fmul_rn(__fsub_rn(x2, x1), (float)(IMG_W - 1)),
                                     (float)(CROP_W - 1));
        const float in_x = __fadd_rn(__fmul_rn(x1, (float)(IMG_W - 1)),
                                     __fmul_rn((float)x, ws));
        s_xv[x] = (in_x >= 0.0f) && (in_x <= (float)(IMG_W - 1));
        const float left = floorf(in_x);
        s_xl[x] = __fsub_rn(in_x, left);
        const float lc = fminf(fmaxf(left, 0.0f), (float)(IMG_W - 1));
        const float rc = fminf(fmaxf(__fadd_rn(left, 1.0f), 0.0f), (float)(IMG_W - 1));
        s_li[x] = (int)lc;
        s_ri[x] = (int)rc;
    }
    __syncthreads();

    const float* __restrict__ img_b = image + (size_t)s_b * (size_t)(IMG_C * PLANE);
    float* __restrict__ out_n = out + (size_t)n * (size_t)OUT_PER_BOX;

    for (int idx = tid; idx < OUT_PER_BOX; idx += 256) {
        const int c = idx / POS;          // constant divisor -> magic mul
        const int p = idx - c * POS;
        const int y = p / CROP_W;
        const int x = p - y * CROP_W;

        float v = 0.0f;
        if (s_yv[y] & s_xv[x]) {
            const float* __restrict__ pl = img_b + c * PLANE;
            const int ti = s_ti[y], bi = s_bi[y];
            const int li = s_li[x], ri = s_ri[x];
            const float tl = pl[ti * IMG_W + li];
            const float tr = pl[ti * IMG_W + ri];
            const float bl = pl[bi * IMG_W + li];
            const float br = pl[bi * IMG_W + ri];
            const float xw = s_xl[x], yw = s_yl[y];
            const float top_v = __fadd_rn(tl, __fmul_rn(__fsub_rn(tr, tl), xw));
            const float bot_v = __fadd_rn(bl, __fmul_rn(__fsub_rn(br, bl), xw));
            v = __fadd_rn(top_v, __fmul_rn(__fsub_rn(bot_v, top_v), yw));
        }
        out_n[idx] = v;
    }
}

extern "C" void kernel_launch(void* const* d_in, const int* in_sizes, int n_in,
                              void* d_out, int out_size, void* d_ws, size_t ws_size,
                              hipStream_t stream) {
    const float* image  = (const float*)d_in[0];
    const float* boxes  = (const float*)d_in[1];
    const int*   boxind = (const int*)d_in[2];
    float* out = (float*)d_out;

    dim3 grid(NBOX);
    dim3 block(256);
    CropAndResize_16630113370849_kernel<<<grid, block, 0, stream>>>(image, boxes, boxind, out);
}

// Round 2
// 206.214 us; speedup vs baseline: 1.3548x; 1.3548x over previous
//
#include <hip/hip_runtime.h>

#define CROP_H 14
#define CROP_W 14
#define IMG_B 8
#define IMG_C 256
#define IMG_H 100
#define IMG_W 152
#define NBOX 1000
#define PLANE (IMG_H * IMG_W)                 // 15200
#define POS (CROP_H * CROP_W)                 // 196
#define OUT_PER_BOX (IMG_C * POS)             // 50176
#define CG 32                                 // channels per block
#define NCG (IMG_C / CG)                      // 8 channel-groups per box

__global__ __launch_bounds__(256) void CropAndResize_16630113370849_kernel(
    const float* __restrict__ image,
    const float* __restrict__ boxes,
    const int* __restrict__ box_ind,
    float* __restrict__ out)
{
    // per-position (196) precomputed gather state
    __shared__ int   s_offTL[POS], s_offTR[POS], s_offBL[POS], s_offBR[POS];
    __shared__ float s_xw[POS], s_yw[POS];
    __shared__ int   s_val[POS];
    __shared__ int   s_b;

    const int bid = blockIdx.x;
    const int n   = bid >> 3;          // box
    const int cg  = bid & 7;           // channel group
    const int tid = threadIdx.x;

    if (tid == 0) s_b = box_ind[n];

    if (tid < POS) {
        const int y = tid / CROP_W;
        const int x = tid - y * CROP_W;

        const float y1 = boxes[n * 4 + 0];
        const float x1 = boxes[n * 4 + 1];
        const float y2 = boxes[n * 4 + 2];
        const float x2 = boxes[n * 4 + 3];

        // exact fp32 round-to-nearest, no FMA — must match numpy bitwise for the
        // discontinuous validity test
        const float hs   = __fdiv_rn(__fmul_rn(__fsub_rn(y2, y1), (float)(IMG_H - 1)),
                                     (float)(CROP_H - 1));
        const float in_y = __fadd_rn(__fmul_rn(y1, (float)(IMG_H - 1)),
                                     __fmul_rn((float)y, hs));
        const int vy = (in_y >= 0.0f) && (in_y <= (float)(IMG_H - 1));
        const float top = floorf(in_y);
        const float ylp = __fsub_rn(in_y, top);
        const int ti = (int)fminf(fmaxf(top, 0.0f), (float)(IMG_H - 1));
        const int bi = (int)fminf(fmaxf(__fadd_rn(top, 1.0f), 0.0f), (float)(IMG_H - 1));

        const float ws   = __fdiv_rn(__fmul_rn(__fsub_rn(x2, x1), (float)(IMG_W - 1)),
                                     (float)(CROP_W - 1));
        const float in_x = __fadd_rn(__fmul_rn(x1, (float)(IMG_W - 1)),
                                     __fmul_rn((float)x, ws));
        const int vx = (in_x >= 0.0f) && (in_x <= (float)(IMG_W - 1));
        const float left = floorf(in_x);
        const float xlp = __fsub_rn(in_x, left);
        const int li = (int)fminf(fmaxf(left, 0.0f), (float)(IMG_W - 1));
        const int ri = (int)fminf(fmaxf(__fadd_rn(left, 1.0f), 0.0f), (float)(IMG_W - 1));

        s_offTL[tid] = ti * IMG_W + li;
        s_offTR[tid] = ti * IMG_W + ri;
        s_offBL[tid] = bi * IMG_W + li;
        s_offBR[tid] = bi * IMG_W + ri;
        s_xw[tid] = xlp;
        s_yw[tid] = ylp;
        s_val[tid] = vy & vx;
    }
    __syncthreads();

    const float* __restrict__ img_b =
        image + (size_t)s_b * (size_t)(IMG_C * PLANE) + (size_t)(cg * CG) * PLANE;
    float* __restrict__ out_n =
        out + (size_t)n * (size_t)OUT_PER_BOX + (size_t)(cg * CG) * POS;

    #pragma unroll 4
    for (int idx = tid; idx < CG * POS; idx += 256) {
        const int cl = idx / POS;         // constant divisor -> magic mul
        const int p  = idx - cl * POS;

        float v = 0.0f;
        if (s_val[p]) {
            const float* __restrict__ pl = img_b + cl * PLANE;
            const float tl = pl[s_offTL[p]];
            const float tr = pl[s_offTR[p]];
            const float bl = pl[s_offBL[p]];
            const float br = pl[s_offBR[p]];
            const float xw = s_xw[p], yw = s_yw[p];
            const float top_v = __fadd_rn(tl, __fmul_rn(__fsub_rn(tr, tl), xw));
            const float bot_v = __fadd_rn(bl, __fmul_rn(__fsub_rn(br, bl), xw));
            v = __fadd_rn(top_v, __fmul_rn(__fsub_rn(bot_v, top_v), yw));
        }
        out_n[idx] = v;
    }
}

extern "C" void kernel_launch(void* const* d_in, const int* in_sizes, int n_in,
                              void* d_out, int out_size, void* d_ws, size_t ws_size,
                              hipStream_t stream) {
    const float* image  = (const float*)d_in[0];
    const float* boxes  = (const float*)d_in[1];
    const int*   boxind = (const int*)d_in[2];
    float* out = (float*)d_out;

    dim3 grid(NBOX * NCG);
    dim3 block(256);
    CropAndResize_16630113370849_kernel<<<grid, block, 0, stream>>>(image, boxes, boxind, out);
}